// Round 16
// baseline (174.464 us; speedup 1.0000x reference)
//
#include <hip/hip_runtime.h>
#include <hip/hip_bf16.h>

// Problem constants (Whisper-style MHA): B=2, S=2048, D=1024, H=16, hd=64
#define BB 2
#define SS 2048
#define DD 1024
#define HH 16
#define HD 64
#define QKSCALE 0.35355339059327373f   // 64^-0.25
// 64^-0.25 * sqrt(log2(e)) : folds exp->exp2 domain change into q,k projections
#define QKSCALE_E2 0.42466090144f
#define NEGBIG (-1e9f)

using u16 = unsigned short;
typedef __attribute__((ext_vector_type(8))) short short8;     // 8 bf16 = 4 VGPR
typedef __attribute__((ext_vector_type(4))) float floatx4;    // MFMA acc
typedef __attribute__((ext_vector_type(4))) unsigned short ushort4v;

#define GLOBAL_AS __attribute__((address_space(1)))
#define LDS_AS __attribute__((address_space(3)))

__device__ __forceinline__ u16 f2b(float f) {          // RNE f32->bf16
  union { float f; unsigned u; } v; v.f = f;
  return (u16)((v.u + 0x7fffu + ((v.u >> 16) & 1u)) >> 16);
}

__device__ __forceinline__ u16 bconv(float f) {        // via HW cvt (fuses to cvt_pk)
  union { __hip_bfloat16 h; u16 u; } cv;
  cv.h = __float2bfloat16(f);
  return cv.u;
}

__device__ __forceinline__ float ex2(float f) {        // raw v_exp_f32 (2^x)
  return __builtin_amdgcn_exp2f(f);
}

__device__ __forceinline__ floatx4 vmax4(floatx4 a, floatx4 b) {
  return (floatx4){fmaxf(a[0], b[0]), fmaxf(a[1], b[1]),
                   fmaxf(a[2], b[2]), fmaxf(a[3], b[3])};
}

__device__ __forceinline__ void gload_lds16(const void* g, void* l) {
  __builtin_amdgcn_global_load_lds((GLOBAL_AS void*)(g), (LDS_AS void*)(l), 16, 0, 0);
}

// ---------------- elementwise f32 -> bf16 ----------------
__global__ __launch_bounds__(256) void cvt_bf16x4(const float4* __restrict__ src,
                                                  ushort4v* __restrict__ dst, int n4) {
  int i = blockIdx.x * 256 + threadIdx.x;
  if (i >= n4) return;
  float4 f = src[i];
  ushort4v o = { f2b(f.x), f2b(f.y), f2b(f.z), f2b(f.w) };
  dst[i] = o;
}

// ------------- weight transpose+convert: W[K][N] f32 -> Wt[N][K] bf16 (4 weights) -------------
__global__ __launch_bounds__(256) void transpose_w(const float* __restrict__ s0,
                                                   const float* __restrict__ s1,
                                                   const float* __restrict__ s2,
                                                   const float* __restrict__ s3,
                                                   u16* __restrict__ dst) {
  __shared__ float tile[32][33];
  const float* src = (blockIdx.z == 0) ? s0 : (blockIdx.z == 1) ? s1
                   : (blockIdx.z == 2) ? s2 : s3;
  u16* d = dst + (size_t)blockIdx.z * 1024 * 1024;
  int c0 = blockIdx.x * 32, r0 = blockIdx.y * 32;
  int tx = threadIdx.x, ty = threadIdx.y;     // block (32,8)
#pragma unroll
  for (int i = 0; i < 4; ++i)
    tile[ty + i * 8][tx] = src[(size_t)(r0 + ty + i * 8) * 1024 + c0 + tx];
  __syncthreads();
#pragma unroll
  for (int i = 0; i < 4; ++i)
    d[(size_t)(c0 + ty + i * 8) * 1024 + r0 + tx] = f2b(tile[tx][ty + i * 8]);
}

// ------------- V [B*S][D] bf16 -> Vt [B*D][S] bf16 (per-batch transpose) -------------
__global__ __launch_bounds__(256) void transpose_v(const u16* __restrict__ v,
                                                   u16* __restrict__ vtd) {
  __shared__ u16 tile[32][34];
  int b = blockIdx.z;
  int c0 = blockIdx.x * 32;   // d
  int s0 = blockIdx.y * 32;   // s
  int tx = threadIdx.x, ty = threadIdx.y;
#pragma unroll
  for (int i = 0; i < 4; ++i)
    tile[ty + i * 8][tx] = v[(size_t)(b * SS + s0 + ty + i * 8) * DD + c0 + tx];
  __syncthreads();
#pragma unroll
  for (int i = 0; i < 4; ++i)
    vtd[(size_t)(b * DD + c0 + ty + i * 8) * SS + s0 + tx] = tile[tx][ty + i * 8];
}

// ------------- out-proj GEMM: 64x128 tile, BK=64, dbuf prefetch, XCD swizzle -------------
template <typename OutT>
__global__ __launch_bounds__(256, 3)
void gemm_bt(const u16* __restrict__ A, const u16* __restrict__ Bt,
             OutT* __restrict__ C, const float* __restrict__ bias,
             float scale, int M, int N, int K) {
  const int tid = threadIdx.x;
  const int lane = tid & 63;
  const int w = tid >> 6;
  const int id = (int)blockIdx.x;
  const int swz = (id & 7) * 64 + (id >> 3);
  const int m0 = (swz & 63) * 64;
  const int n0 = (swz >> 6) * 128;
  __shared__ u16 As[2][64 * 64];     // 8KB per buf
  __shared__ u16 Bs[2][128 * 64];    // 16KB per buf
  floatx4 acc[2][4];
#pragma unroll
  for (int i = 0; i < 2; ++i)
#pragma unroll
    for (int j = 0; j < 4; ++j) acc[i][j] = (floatx4){0.f, 0.f, 0.f, 0.f};

  const int wr = (w >> 1) * 32;
  const int wc = (w & 1) * 64;
  const int g = lane >> 4;
  const int lr = lane & 15;
  const size_t strideA = (size_t)K * 2;

  auto stage = [&](int k0, int buf) {
#pragma unroll
    for (int p = 0; p < 2; ++p) {    // A: 8KB
      int L = tid * 16 + p * 4096;
      int row = L >> 7;
      int cb = (L ^ ((row & 7) << 4)) & 127;
      gload_lds16((const char*)A + (size_t)(m0 + row) * strideA + k0 * 2 + cb,
                  (char*)As[buf] + p * 4096 + w * 1024);
    }
#pragma unroll
    for (int p = 0; p < 4; ++p) {    // B: 16KB
      int L = tid * 16 + p * 4096;
      int row = L >> 7;
      int cb = (L ^ ((row & 7) << 4)) & 127;
      gload_lds16((const char*)Bt + (size_t)(n0 + row) * strideA + k0 * 2 + cb,
                  (char*)Bs[buf] + p * 4096 + w * 1024);
    }
  };

  const int nsteps = K >> 6;
  stage(0, 0);
  for (int t = 0; t < nsteps; ++t) {
    const int buf = t & 1;
    __syncthreads();                       // drains stage(t); guards buf reuse
    if (t + 1 < nsteps) stage((t + 1) << 6, buf ^ 1);
    const u16* as = As[buf];
    const u16* bs = Bs[buf];
#pragma unroll
    for (int ks = 0; ks < 2; ++ks) {
      short8 af[2], bf[4];
      const int c0 = ks * 32 + g * 8;
#pragma unroll
      for (int mi = 0; mi < 2; ++mi) {
        int row = wr + mi * 16 + lr;
        af[mi] = *(const short8*)(as + row * 64 + (c0 ^ ((row & 7) << 3)));
      }
#pragma unroll
      for (int ni = 0; ni < 4; ++ni) {
        int row = wc + ni * 16 + lr;
        bf[ni] = *(const short8*)(bs + row * 64 + (c0 ^ ((row & 7) << 3)));
      }
      __builtin_amdgcn_s_setprio(1);
#pragma unroll
      for (int mi = 0; mi < 2; ++mi)
#pragma unroll
        for (int ni = 0; ni < 4; ++ni)
          acc[mi][ni] = __builtin_amdgcn_mfma_f32_16x16x32_bf16(af[mi], bf[ni],
                                                                acc[mi][ni], 0, 0, 0);
      __builtin_amdgcn_s_setprio(0);
    }
  }
#pragma unroll
  for (int ni = 0; ni < 4; ++ni) {
    int col = n0 + wc + ni * 16 + lr;
    float bvv = bias ? bias[col] : 0.f;
#pragma unroll
    for (int mi = 0; mi < 2; ++mi) {
#pragma unroll
      for (int r = 0; r < 4; ++r) {
        int rowg = m0 + wr + mi * 16 + g * 4 + r;
        float val = (acc[mi][ni][r] + bvv) * scale;
        if constexpr (sizeof(OutT) == 4) C[(size_t)rowg * N + col] = val;
        else C[(size_t)rowg * N + col] = (OutT)f2b(val);
      }
    }
  }
}

// ------------- fused QKV GEMM: 128x128 tile, BK=32 dbuf, XCD swizzle, LDS-bounce epilogue ------
__global__ __launch_bounds__(256, 4)
void gemm_qkv(const u16* __restrict__ A, const u16* __restrict__ Wt3,
              u16* __restrict__ Out3, const float* __restrict__ bq,
              const float* __restrict__ bv) {
  const int id = (int)blockIdx.x;
  const int swz = (id & 7) * 96 + (id >> 3);
  const int bx = swz & 31;
  const int rest = swz >> 5;
  const int by = rest & 7;
  const int seg = rest >> 3;
  const u16* Bt = Wt3 + (size_t)seg * 1024 * 1024;
  u16* C = Out3 + (size_t)seg * 4096 * 1024;
  const float* bias = (seg == 0) ? bq : (seg == 2) ? bv : nullptr;
  const float scale = (seg == 2) ? 1.0f : QKSCALE_E2;   // exp2-domain fold

  const int tid = threadIdx.x;
  const int lane = tid & 63;
  const int w = tid >> 6;
  const int m0 = bx * 128;
  const int n0 = by * 128;
  __shared__ u16 As[2][64 * 64];   // 8KB per buf (128 logical rows x 32 cols, row-paired)
  __shared__ u16 Bs[2][64 * 64];
  floatx4 acc[4][4];
#pragma unroll
  for (int i = 0; i < 4; ++i)
#pragma unroll
    for (int j = 0; j < 4; ++j) acc[i][j] = (floatx4){0.f, 0.f, 0.f, 0.f};
  const int wr = (w >> 1) * 64;
  const int wc = (w & 1) * 64;
  const int g = lane >> 4;
  const int lr = lane & 15;

  auto stage = [&](int k0, int buf) {
#pragma unroll
    for (int p = 0; p < 2; ++p) {
      int L = tid * 16 + p * 4096;
      int lrow = L >> 7;                      // 0..63 LDS row (128B)
      int un = (L & 127) ^ ((lrow & 7) << 4); // un-swizzled intra-row byte
      int r = lrow * 2 + (un >> 6);           // logical row 0..127
      int cb = un & 63;                       // k-byte 0..63 (32 elems)
      gload_lds16((const char*)A + (size_t)(m0 + r) * 2048 + k0 * 2 + cb,
                  (char*)As[buf] + p * 4096 + w * 1024);
      gload_lds16((const char*)Bt + (size_t)(n0 + r) * 2048 + k0 * 2 + cb,
                  (char*)Bs[buf] + p * 4096 + w * 1024);
    }
  };

  stage(0, 0);
  for (int t = 0; t < 32; ++t) {             // 32 K-steps of 32
    const int buf = t & 1;
    __syncthreads();                         // drains stage(t); guards buf reuse
    if (t + 1 < 32) stage((t + 1) << 5, buf ^ 1);
    const u16* as = As[buf];
    const u16* bs = Bs[buf];
    short8 af[4], bf[4];
#pragma unroll
    for (int mi = 0; mi < 4; ++mi) {
      int r = wr + mi * 16 + lr;
      af[mi] = *(const short8*)((const char*)as +
               ((r >> 1) * 128 + ((((r & 1) << 6) | (g * 16)) ^ (((r >> 1) & 7) << 4))));
    }
#pragma unroll
    for (int ni = 0; ni < 4; ++ni) {
      int r = wc + ni * 16 + lr;
      bf[ni] = *(const short8*)((const char*)bs +
               ((r >> 1) * 128 + ((((r & 1) << 6) | (g * 16)) ^ (((r >> 1) & 7) << 4))));
    }
    __builtin_amdgcn_s_setprio(1);
#pragma unroll
    for (int mi = 0; mi < 4; ++mi)
#pragma unroll
      for (int ni = 0; ni < 4; ++ni)
        acc[mi][ni] = __builtin_amdgcn_mfma_f32_16x16x32_bf16(af[mi], bf[ni],
                                                              acc[mi][ni], 0, 0, 0);
    __builtin_amdgcn_s_setprio(0);
  }

  // ---- coalesced epilogue via per-wave LDS bounce ----
  __syncthreads();                            // all K-loop LDS reads done
  u16* eb = (w == 0) ? (u16*)As[0] : (w == 1) ? (u16*)As[1]
          : (w == 2) ? (u16*)Bs[0] : (u16*)Bs[1];   // 8KB per wave; use [16][72]
  const int rr = lane >> 2;                   // 0..15 (row within 16-row strip)
  const int cc = lane & 3;                    // 0..3  (16-col chunk)
  float bv4[4];
#pragma unroll
  for (int ni = 0; ni < 4; ++ni)
    bv4[ni] = bias ? bias[n0 + wc + ni * 16 + lr] : 0.f;
#pragma unroll
  for (int mi = 0; mi < 4; ++mi) {
#pragma unroll
    for (int ni = 0; ni < 4; ++ni)
#pragma unroll
      for (int r = 0; r < 4; ++r)
        eb[(g * 4 + r) * 72 + ni * 16 + lr] =
            f2b((acc[mi][ni][r] + bv4[ni]) * scale);
    short8 v0 = *(const short8*)(eb + rr * 72 + cc * 16);
    short8 v1 = *(const short8*)(eb + rr * 72 + cc * 16 + 8);
    u16* dst = C + (size_t)(m0 + wr + mi * 16 + rr) * 1024 + n0 + wc + cc * 16;
    *(short8*)dst = v0;
    *(short8*)(dst + 8) = v1;
  }
}

// ------------- flash attention: BARRIER-FREE, 1 wave/block, 32 q-rows (2 groups) -------------
// No K/V LDS staging: fragments read straight from global (L2-resident: 512KB/head x 4
// heads/XCD). Two 16-row groups share each K/V fragment set (halves L2 traffic). P keeps
// the per-wave LDS round-trip (lgkm-ordered, no barrier). Zero __syncthreads -> no
// lockstep coupling, no vmcnt(0) drains; each wave streams independently.
__device__ __forceinline__ void stream_softmax(floatx4 (&sa)[4], float& m, float& l,
                                               floatx4 (&acc)[4], u16* pl,
                                               bool diag, int wl, int g, int lr) {
  if (diag) {
#pragma unroll
    for (int ct = 0; ct < 4; ++ct)
#pragma unroll
      for (int r = 0; r < 4; ++r)
        if (ct * 16 + g * 4 + r > wl) sa[ct][r] += NEGBIG;
  }
  floatx4 v = vmax4(vmax4(sa[0], sa[1]), vmax4(sa[2], sa[3]));
  float mx = fmaxf(fmaxf(v[0], v[1]), fmaxf(v[2], v[3]));
  mx = fmaxf(mx, __shfl_xor(mx, 16, 64));
  mx = fmaxf(mx, __shfl_xor(mx, 32, 64));
  if (!__all(mx <= m + 8.f)) {
    float mn = fmaxf(m, mx);
    float al = ex2(m - mn);
    l *= al;
#pragma unroll
    for (int dt = 0; dt < 4; ++dt) acc[dt] *= al;
    m = mn;
  }
  floatx4 p[4];
#pragma unroll
  for (int ct = 0; ct < 4; ++ct)
#pragma unroll
    for (int r = 0; r < 4; ++r)
      p[ct][r] = ex2(sa[ct][r] - m);
  floatx4 s = (p[0] + p[1]) + (p[2] + p[3]);
  float rs = (s[0] + s[1]) + (s[2] + s[3]);
  rs += __shfl_xor(rs, 16, 64);
  rs += __shfl_xor(rs, 32, 64);
  l += rs;
#pragma unroll
  for (int ct = 0; ct < 4; ++ct) {
    ushort4v pk = { bconv(p[ct][0]), bconv(p[ct][1]),
                    bconv(p[ct][2]), bconv(p[ct][3]) };
    *(ushort4v*)((char*)pl + ((lr * 128 + ct * 32 + g * 8) ^ ((lr & 7) << 4))) = pk;
  }
}

__global__ __launch_bounds__(64)
void flash_attn(const u16* __restrict__ q, const u16* __restrict__ k,
                const u16* __restrict__ vt, u16* __restrict__ o) {
  const int lane = threadIdx.x;       // 64-thread block = 1 wave
  const int g = lane >> 4;
  const int lr = lane & 15;
  // mapping: XCD x gets heads 4x..4x+3; within a head, consecutive idx pair long/short
  // row-groups (nt sums ~33) so any contiguous co-resident set is balanced.
  const int i = (int)blockIdx.x;      // 0..2047
  const int x = i & 7;
  const int rest = i >> 3;            // 0..255
  const int head = x * 4 + (rest >> 6);
  const int idx = rest & 63;          // 0..63
  const int b = head >> 4;
  const int h = head & 15;
  const int j = (idx & 1) ? (idx >> 1) : (63 - (idx >> 1));
  const int R = j * 32;               // first of 32 q-rows
  const int nt = ((R + 31) >> 6) + 1; // KV tiles of 64
  const int dT = nt - 1;              // diagonal tile
  const int RA = R, RB = R + 16;
  const int wlA = (RA & 63);          // local diag threshold base (add lr per lane)
  const int wlB = (RB & 63);

  __shared__ u16 Pl[2][16 * 64];      // 4KB: per-group P^T

  short8 qfA[2], qfB[2];
  {
    const u16* qa = q + (size_t)(b * SS + RA + lr) * DD + h * HD + g * 8;
    qfA[0] = *(const short8*)qa;
    qfA[1] = *(const short8*)(qa + 32);
    const u16* qb = q + (size_t)(b * SS + RB + lr) * DD + h * HD + g * 8;
    qfB[0] = *(const short8*)qb;
    qfB[1] = *(const short8*)(qb + 32);
  }
  floatx4 accA[4], accB[4];
#pragma unroll
  for (int dt = 0; dt < 4; ++dt) {
    accA[dt] = (floatx4){0.f, 0.f, 0.f, 0.f};
    accB[dt] = (floatx4){0.f, 0.f, 0.f, 0.f};
  }
  float mA = -1e30f, lA = 0.f, mB = -1e30f, lB = 0.f;

  const char* kbase = (const char*)(k + (size_t)(b * SS) * DD + h * HD);
  const char* vbase = (const char*)(vt + (size_t)((b * HH + h) * HD) * SS);

  for (int t = 0; t < nt; ++t) {
    const int kvb = t * 64;
    // K fragments straight from global (L2-hit): kf[ks*4+ct]
    short8 kf[8];
#pragma unroll
    for (int ks = 0; ks < 2; ++ks)
#pragma unroll
      for (int ct = 0; ct < 4; ++ct)
        kf[ks * 4 + ct] = *(const short8*)(kbase +
            (size_t)(kvb + ct * 16 + lr) * (DD * 2) + (ks * 32 + g * 8) * 2);

    floatx4 saA[4], saB[4];
#pragma unroll
    for (int ct = 0; ct < 4; ++ct) {
      saA[ct] = (floatx4){0.f, 0.f, 0.f, 0.f};
      saB[ct] = (floatx4){0.f, 0.f, 0.f, 0.f};
    }
    __builtin_amdgcn_s_setprio(1);
#pragma unroll
    for (int ks = 0; ks < 2; ++ks)
#pragma unroll
      for (int ct = 0; ct < 4; ++ct) {
        saA[ct] = __builtin_amdgcn_mfma_f32_16x16x32_bf16(kf[ks * 4 + ct], qfA[ks],
                                                          saA[ct], 0, 0, 0);
        saB[ct] = __builtin_amdgcn_mfma_f32_16x16x32_bf16(kf[ks * 4 + ct], qfB[ks],
                                                          saB[ct], 0, 0, 0);
      }
    __builtin_amdgcn_s_setprio(0);

    // V fragments issued before softmax so their latency hides under it
    short8 vf[8];
#pragma unroll
    for (int ks = 0; ks < 2; ++ks)
#pragma unroll
      for (int dt = 0; dt < 4; ++dt)
        vf[ks * 4 + dt] = *(const short8*)(vbase +
            (size_t)(dt * 16 + lr) * (SS * 2) + (kvb + ks * 32 + g * 8) * 2);

    stream_softmax(saA, mA, lA, accA, Pl[0], t == dT, wlA + lr, g, lr);
    stream_softmax(saB, mB, lB, accB, Pl[1], t == dT, wlB + lr, g, lr);

    __builtin_amdgcn_s_setprio(1);
#pragma unroll
    for (int ks = 0; ks < 2; ++ks) {
      int pby = (lr * 128 + ks * 64 + g * 16) ^ ((lr & 7) << 4);
      short8 pfA = *(const short8*)((const char*)Pl[0] + pby);
      short8 pfB = *(const short8*)((const char*)Pl[1] + pby);
#pragma unroll
      for (int dt = 0; dt < 4; ++dt) {
        accA[dt] = __builtin_amdgcn_mfma_f32_16x16x32_bf16(vf[ks * 4 + dt], pfA,
                                                           accA[dt], 0, 0, 0);
        accB[dt] = __builtin_amdgcn_mfma_f32_16x16x32_bf16(vf[ks * 4 + dt], pfB,
                                                           accB[dt], 0, 0, 0);
      }
    }
    __builtin_amdgcn_s_setprio(0);
  }

  float invA = 1.0f / lA;
  float invB = 1.0f / lB;
#pragma unroll
  for (int dt = 0; dt < 4; ++dt) {
    ushort4v pa = { bconv(accA[dt][0] * invA), bconv(accA[dt][1] * invA),
                    bconv(accA[dt][2] * invA), bconv(accA[dt][3] * invA) };
    ushort4v pb = { bconv(accB[dt][0] * invB), bconv(accB[dt][1] * invB),
                    bconv(accB[dt][2] * invB), bconv(accB[dt][3] * invB) };
    *(ushort4v*)(o + (size_t)(b * SS + RA + lr) * DD + h * HD + dt * 16 + g * 4) = pa;
    *(ushort4v*)(o + (size_t)(b * SS + RB + lr) * DD + h * HD + dt * 16 + g * 4) = pb;
  }
}

extern "C" void kernel_launch(void* const* d_in, const int* in_sizes, int n_in,
                              void* d_out, int out_size, void* d_ws, size_t ws_size,
                              hipStream_t stream) {
  const float* x  = (const float*)d_in[0];
  // d_in[1] = mask: causal additive -1e9, replicated analytically in-kernel
  const float* Wq = (const float*)d_in[2];
  const float* bq = (const float*)d_in[3];
  const float* Wk = (const float*)d_in[4];
  const float* Wv = (const float*)d_in[5];
  const float* bv = (const float*)d_in[6];
  const float* Wo = (const float*)d_in[7];
  const float* bo = (const float*)d_in[8];
  float* out = (float*)d_out;

  char* ws = (char*)d_ws;
  u16* xb  = (u16*)(ws);                    // 8MB  x bf16 [4096][1024]
  u16* wt  = (u16*)(ws + (8u << 20));       // 8MB  Wq^T,Wk^T,Wv^T,Wo^T bf16
  u16* qkv = (u16*)(ws + (16u << 20));      // 24MB q,k,v bf16 [4096][1024] each
  u16* vb  = qkv + 2u * 4096 * 1024;
  u16* vtb = (u16*)(ws + (40u << 20));      // 8MB  v^T per batch [B*D][S]
  u16* ob  = (u16*)(ws + (48u << 20));      // 8MB  attn out bf16
  u16* wot = wt + 3u * 1024 * 1024;

  dim3 tb(32, 8);
  cvt_bf16x4<<<4096, 256, 0, stream>>>((const float4*)x, (ushort4v*)xb,
                                       (BB * SS * DD) / 4);
  transpose_w<<<dim3(32, 32, 4), tb, 0, stream>>>(Wq, Wk, Wv, Wo, wt);
  gemm_qkv<<<768, 256, 0, stream>>>(xb, wt, qkv, bq, bv);
  transpose_v<<<dim3(32, 64, 2), tb, 0, stream>>>(vb, vtb);
  flash_attn<<<2048, 64, 0, stream>>>(qkv, qkv + (size_t)4096 * 1024, vtb, ob);
  gemm_bt<float><<<512, 256, 0, stream>>>(ob, wot, out, bo, 1.0f,
                                          4096, 1024, 1024);
}

// Round 17
// 109.527 us; speedup vs baseline: 1.5929x; 1.5929x over previous
//
#include <hip/hip_runtime.h>
#include <hip/hip_bf16.h>

// Problem constants (Whisper-style MHA): B=2, S=2048, D=1024, H=16, hd=64
#define BB 2
#define SS 2048
#define DD 1024
#define HH 16
#define HD 64
#define QKSCALE 0.35355339059327373f   // 64^-0.25
// 64^-0.25 * sqrt(log2(e)) : folds exp->exp2 domain change into q,k projections
#define QKSCALE_E2 0.42466090144f
#define NEGBIG (-1e9f)

using u16 = unsigned short;
typedef __attribute__((ext_vector_type(8))) short short8;     // 8 bf16 = 4 VGPR
typedef __attribute__((ext_vector_type(4))) float floatx4;    // MFMA acc
typedef __attribute__((ext_vector_type(4))) unsigned short ushort4v;

#define GLOBAL_AS __attribute__((address_space(1)))
#define LDS_AS __attribute__((address_space(3)))

__device__ __forceinline__ u16 f2b(float f) {          // RNE f32->bf16
  union { float f; unsigned u; } v; v.f = f;
  return (u16)((v.u + 0x7fffu + ((v.u >> 16) & 1u)) >> 16);
}

__device__ __forceinline__ u16 bconv(float f) {        // via HW cvt (fuses to cvt_pk)
  union { __hip_bfloat16 h; u16 u; } cv;
  cv.h = __float2bfloat16(f);
  return cv.u;
}

__device__ __forceinline__ float ex2(float f) {        // raw v_exp_f32 (2^x)
  return __builtin_amdgcn_exp2f(f);
}

__device__ __forceinline__ floatx4 vmax4(floatx4 a, floatx4 b) {
  return (floatx4){fmaxf(a[0], b[0]), fmaxf(a[1], b[1]),
                   fmaxf(a[2], b[2]), fmaxf(a[3], b[3])};
}

__device__ __forceinline__ void gload_lds16(const void* g, void* l) {
  __builtin_amdgcn_global_load_lds((GLOBAL_AS void*)(g), (LDS_AS void*)(l), 16, 0, 0);
}

// ---------------- elementwise f32 -> bf16 ----------------
__global__ __launch_bounds__(256) void cvt_bf16x4(const float4* __restrict__ src,
                                                  ushort4v* __restrict__ dst, int n4) {
  int i = blockIdx.x * 256 + threadIdx.x;
  if (i >= n4) return;
  float4 f = src[i];
  ushort4v o = { f2b(f.x), f2b(f.y), f2b(f.z), f2b(f.w) };
  dst[i] = o;
}

// ------------- weight transpose+convert: W[K][N] f32 -> Wt[N][K] bf16 (4 weights) -------------
__global__ __launch_bounds__(256) void transpose_w(const float* __restrict__ s0,
                                                   const float* __restrict__ s1,
                                                   const float* __restrict__ s2,
                                                   const float* __restrict__ s3,
                                                   u16* __restrict__ dst) {
  __shared__ float tile[32][33];
  const float* src = (blockIdx.z == 0) ? s0 : (blockIdx.z == 1) ? s1
                   : (blockIdx.z == 2) ? s2 : s3;
  u16* d = dst + (size_t)blockIdx.z * 1024 * 1024;
  int c0 = blockIdx.x * 32, r0 = blockIdx.y * 32;
  int tx = threadIdx.x, ty = threadIdx.y;     // block (32,8)
#pragma unroll
  for (int i = 0; i < 4; ++i)
    tile[ty + i * 8][tx] = src[(size_t)(r0 + ty + i * 8) * 1024 + c0 + tx];
  __syncthreads();
#pragma unroll
  for (int i = 0; i < 4; ++i)
    d[(size_t)(c0 + ty + i * 8) * 1024 + r0 + tx] = f2b(tile[tx][ty + i * 8]);
}

// ------------- out-proj GEMM: 64x128 tile, BK=64, dbuf prefetch, XCD swizzle -------------
template <typename OutT>
__global__ __launch_bounds__(256, 3)
void gemm_bt(const u16* __restrict__ A, const u16* __restrict__ Bt,
             OutT* __restrict__ C, const float* __restrict__ bias,
             float scale, int M, int N, int K) {
  const int tid = threadIdx.x;
  const int lane = tid & 63;
  const int w = tid >> 6;
  const int id = (int)blockIdx.x;
  const int swz = (id & 7) * 64 + (id >> 3);
  const int m0 = (swz & 63) * 64;
  const int n0 = (swz >> 6) * 128;
  __shared__ u16 As[2][64 * 64];     // 8KB per buf
  __shared__ u16 Bs[2][128 * 64];    // 16KB per buf
  floatx4 acc[2][4];
#pragma unroll
  for (int i = 0; i < 2; ++i)
#pragma unroll
    for (int j = 0; j < 4; ++j) acc[i][j] = (floatx4){0.f, 0.f, 0.f, 0.f};

  const int wr = (w >> 1) * 32;
  const int wc = (w & 1) * 64;
  const int g = lane >> 4;
  const int lr = lane & 15;
  const size_t strideA = (size_t)K * 2;

  auto stage = [&](int k0, int buf) {
#pragma unroll
    for (int p = 0; p < 2; ++p) {    // A: 8KB
      int L = tid * 16 + p * 4096;
      int row = L >> 7;
      int cb = (L ^ ((row & 7) << 4)) & 127;
      gload_lds16((const char*)A + (size_t)(m0 + row) * strideA + k0 * 2 + cb,
                  (char*)As[buf] + p * 4096 + w * 1024);
    }
#pragma unroll
    for (int p = 0; p < 4; ++p) {    // B: 16KB
      int L = tid * 16 + p * 4096;
      int row = L >> 7;
      int cb = (L ^ ((row & 7) << 4)) & 127;
      gload_lds16((const char*)Bt + (size_t)(n0 + row) * strideA + k0 * 2 + cb,
                  (char*)Bs[buf] + p * 4096 + w * 1024);
    }
  };

  const int nsteps = K >> 6;
  stage(0, 0);
  for (int t = 0; t < nsteps; ++t) {
    const int buf = t & 1;
    __syncthreads();                       // drains stage(t); guards buf reuse
    if (t + 1 < nsteps) stage((t + 1) << 6, buf ^ 1);
    const u16* as = As[buf];
    const u16* bs = Bs[buf];
#pragma unroll
    for (int ks = 0; ks < 2; ++ks) {
      short8 af[2], bf[4];
      const int c0 = ks * 32 + g * 8;
#pragma unroll
      for (int mi = 0; mi < 2; ++mi) {
        int row = wr + mi * 16 + lr;
        af[mi] = *(const short8*)(as + row * 64 + (c0 ^ ((row & 7) << 3)));
      }
#pragma unroll
      for (int ni = 0; ni < 4; ++ni) {
        int row = wc + ni * 16 + lr;
        bf[ni] = *(const short8*)(bs + row * 64 + (c0 ^ ((row & 7) << 3)));
      }
      __builtin_amdgcn_s_setprio(1);
#pragma unroll
      for (int mi = 0; mi < 2; ++mi)
#pragma unroll
        for (int ni = 0; ni < 4; ++ni)
          acc[mi][ni] = __builtin_amdgcn_mfma_f32_16x16x32_bf16(af[mi], bf[ni],
                                                                acc[mi][ni], 0, 0, 0);
      __builtin_amdgcn_s_setprio(0);
    }
  }
#pragma unroll
  for (int ni = 0; ni < 4; ++ni) {
    int col = n0 + wc + ni * 16 + lr;
    float bvv = bias ? bias[col] : 0.f;
#pragma unroll
    for (int mi = 0; mi < 2; ++mi) {
#pragma unroll
      for (int r = 0; r < 4; ++r) {
        int rowg = m0 + wr + mi * 16 + g * 4 + r;
        float val = (acc[mi][ni][r] + bvv) * scale;
        if constexpr (sizeof(OutT) == 4) C[(size_t)rowg * N + col] = val;
        else C[(size_t)rowg * N + col] = (OutT)f2b(val);
      }
    }
  }
}

// ------------- fused QKV GEMM: 128x128 tile, BK=32 dbuf, XCD swizzle -------------
// seg 0/1 (q,k): coalesced store via per-wave LDS bounce.
// seg 2 (v): store DIRECTLY transposed into vtb[b*1024+d][s] (8B per (mi,ni) per lane;
// g-groups tile 32B row segments, merged to full lines in L2) -> transpose_v eliminated.
__global__ __launch_bounds__(256, 4)
void gemm_qkv(const u16* __restrict__ A, const u16* __restrict__ Wt3,
              u16* __restrict__ Out3, u16* __restrict__ Vt,
              const float* __restrict__ bq, const float* __restrict__ bv) {
  const int id = (int)blockIdx.x;
  const int swz = (id & 7) * 96 + (id >> 3);
  const int bx = swz & 31;
  const int rest = swz >> 5;
  const int by = rest & 7;
  const int seg = rest >> 3;
  const u16* Bt = Wt3 + (size_t)seg * 1024 * 1024;
  u16* C = Out3 + (size_t)seg * 4096 * 1024;
  const float* bias = (seg == 0) ? bq : (seg == 2) ? bv : nullptr;
  const float scale = (seg == 2) ? 1.0f : QKSCALE_E2;   // exp2-domain fold

  const int tid = threadIdx.x;
  const int lane = tid & 63;
  const int w = tid >> 6;
  const int m0 = bx * 128;
  const int n0 = by * 128;
  __shared__ u16 As[2][64 * 64];   // 8KB per buf (128 logical rows x 32 cols, row-paired)
  __shared__ u16 Bs[2][64 * 64];
  floatx4 acc[4][4];
#pragma unroll
  for (int i = 0; i < 4; ++i)
#pragma unroll
    for (int j = 0; j < 4; ++j) acc[i][j] = (floatx4){0.f, 0.f, 0.f, 0.f};
  const int wr = (w >> 1) * 64;
  const int wc = (w & 1) * 64;
  const int g = lane >> 4;
  const int lr = lane & 15;

  auto stage = [&](int k0, int buf) {
#pragma unroll
    for (int p = 0; p < 2; ++p) {
      int L = tid * 16 + p * 4096;
      int lrow = L >> 7;                      // 0..63 LDS row (128B)
      int un = (L & 127) ^ ((lrow & 7) << 4); // un-swizzled intra-row byte
      int r = lrow * 2 + (un >> 6);           // logical row 0..127
      int cb = un & 63;                       // k-byte 0..63 (32 elems)
      gload_lds16((const char*)A + (size_t)(m0 + r) * 2048 + k0 * 2 + cb,
                  (char*)As[buf] + p * 4096 + w * 1024);
      gload_lds16((const char*)Bt + (size_t)(n0 + r) * 2048 + k0 * 2 + cb,
                  (char*)Bs[buf] + p * 4096 + w * 1024);
    }
  };

  stage(0, 0);
  for (int t = 0; t < 32; ++t) {             // 32 K-steps of 32
    const int buf = t & 1;
    __syncthreads();                         // drains stage(t); guards buf reuse
    if (t + 1 < 32) stage((t + 1) << 5, buf ^ 1);
    const u16* as = As[buf];
    const u16* bs = Bs[buf];
    short8 af[4], bf[4];
#pragma unroll
    for (int mi = 0; mi < 4; ++mi) {
      int r = wr + mi * 16 + lr;
      af[mi] = *(const short8*)((const char*)as +
               ((r >> 1) * 128 + ((((r & 1) << 6) | (g * 16)) ^ (((r >> 1) & 7) << 4))));
    }
#pragma unroll
    for (int ni = 0; ni < 4; ++ni) {
      int r = wc + ni * 16 + lr;
      bf[ni] = *(const short8*)((const char*)bs +
               ((r >> 1) * 128 + ((((r & 1) << 6) | (g * 16)) ^ (((r >> 1) & 7) << 4))));
    }
    __builtin_amdgcn_s_setprio(1);
#pragma unroll
    for (int mi = 0; mi < 4; ++mi)
#pragma unroll
      for (int ni = 0; ni < 4; ++ni)
        acc[mi][ni] = __builtin_amdgcn_mfma_f32_16x16x32_bf16(af[mi], bf[ni],
                                                              acc[mi][ni], 0, 0, 0);
    __builtin_amdgcn_s_setprio(0);
  }

  if (seg == 2) {
    // ---- direct V^T epilogue: vtb[bseg*1024 + d][s], 8B stores (4 s-consecutive) ----
    const int bseg = m0 >> 11;                 // batch of this block (tile never straddles)
    const int s0 = (m0 & 2047) + wr + g * 4;   // s base for this lane's rows
#pragma unroll
    for (int ni = 0; ni < 4; ++ni) {
      int d = n0 + wc + ni * 16 + lr;
      float bvv = bv[d];
      u16* vrow = Vt + (size_t)(bseg * 1024 + d) * 2048;
#pragma unroll
      for (int mi = 0; mi < 4; ++mi) {
        ushort4v pk = { f2b(acc[mi][ni][0] + bvv), f2b(acc[mi][ni][1] + bvv),
                        f2b(acc[mi][ni][2] + bvv), f2b(acc[mi][ni][3] + bvv) };
        *(ushort4v*)(vrow + s0 + mi * 16) = pk;
      }
    }
    return;                                    // block-uniform: no barrier divergence
  }

  // ---- coalesced epilogue via per-wave LDS bounce (seg 0/1) ----
  __syncthreads();                            // all K-loop LDS reads done
  u16* eb = (w == 0) ? (u16*)As[0] : (w == 1) ? (u16*)As[1]
          : (w == 2) ? (u16*)Bs[0] : (u16*)Bs[1];   // 8KB per wave; use [16][72]
  const int rr = lane >> 2;                   // 0..15 (row within 16-row strip)
  const int cc = lane & 3;                    // 0..3  (16-col chunk)
  float bv4[4];
#pragma unroll
  for (int ni = 0; ni < 4; ++ni)
    bv4[ni] = bias ? bias[n0 + wc + ni * 16 + lr] : 0.f;
#pragma unroll
  for (int mi = 0; mi < 4; ++mi) {
#pragma unroll
    for (int ni = 0; ni < 4; ++ni)
#pragma unroll
      for (int r = 0; r < 4; ++r)
        eb[(g * 4 + r) * 72 + ni * 16 + lr] =
            f2b((acc[mi][ni][r] + bv4[ni]) * scale);
    short8 v0 = *(const short8*)(eb + rr * 72 + cc * 16);
    short8 v1 = *(const short8*)(eb + rr * 72 + cc * 16 + 8);
    u16* dst = C + (size_t)(m0 + wr + mi * 16 + rr) * 1024 + n0 + wc + cc * 16;
    *(short8*)dst = v0;
    *(short8*)(dst + 8) = v1;
  }
}

// ------------- flash attention: swapped-QK (S^T), single stream, 1 q-tile/block -------------
// (round-10 version: P via LDS, 40KB, 4 blocks/CU, balanced qt mapping)
__device__ __forceinline__ void stream_softmax(floatx4 (&sa)[4], float& m, float& l,
                                               floatx4 (&acc)[4], u16* pl,
                                               bool diag, int wlr, int g, int lr) {
  if (diag) {
#pragma unroll
    for (int ct = 0; ct < 4; ++ct)
#pragma unroll
      for (int r = 0; r < 4; ++r)
        if (ct * 16 + g * 4 + r > wlr) sa[ct][r] += NEGBIG;
  }
  floatx4 v = vmax4(vmax4(sa[0], sa[1]), vmax4(sa[2], sa[3]));
  float mx = fmaxf(fmaxf(v[0], v[1]), fmaxf(v[2], v[3]));
  mx = fmaxf(mx, __shfl_xor(mx, 16, 64));
  mx = fmaxf(mx, __shfl_xor(mx, 32, 64));
  if (!__all(mx <= m + 8.f)) {
    float mn = fmaxf(m, mx);
    float al = ex2(m - mn);
    l *= al;
#pragma unroll
    for (int dt = 0; dt < 4; ++dt) acc[dt] *= al;
    m = mn;
  }
  floatx4 p[4];
#pragma unroll
  for (int ct = 0; ct < 4; ++ct)
#pragma unroll
    for (int r = 0; r < 4; ++r)
      p[ct][r] = ex2(sa[ct][r] - m);
  floatx4 s = (p[0] + p[1]) + (p[2] + p[3]);
  float rs = (s[0] + s[1]) + (s[2] + s[3]);
  rs += __shfl_xor(rs, 16, 64);
  rs += __shfl_xor(rs, 32, 64);
  l += rs;
#pragma unroll
  for (int ct = 0; ct < 4; ++ct) {
    ushort4v pk = { bconv(p[ct][0]), bconv(p[ct][1]),
                    bconv(p[ct][2]), bconv(p[ct][3]) };
    *(ushort4v*)((char*)pl + ((lr * 128 + ct * 32 + g * 8) ^ ((lr & 7) << 4))) = pk;
  }
}

__global__ __launch_bounds__(256, 4)
void flash_attn(const u16* __restrict__ q, const u16* __restrict__ k,
                const u16* __restrict__ vt, u16* __restrict__ o) {
  const int tid = threadIdx.x;
  const int lane = tid & 63;
  const int w = tid >> 6;
  const int g = lane >> 4;
  const int lr = lane & 15;
  const int i = (int)blockIdx.x;      // 0..1023
  const int x = i & 7;
  const int kk = i >> 3;              // 0..127
  const int s = kk & 3;
  const int mI = kk >> 2;             // 0..31
  const int u = mI >> 3;
  const int v = mI & 7;
  const int gg = x * 4 + s;           // (b,h), 4 groups per XCD stream
  const int b = gg >> 4;
  const int h = gg & 15;
  const int a = (u + s) & 3;
  const int qt = (a == 0) ? v : (a == 1) ? (31 - v) : (a == 2) ? (16 + v) : (15 - v);
  const int row0 = qt * 64 + w * 16;
  const int wlr = w * 16 + lr;

  __shared__ u16 Ks[2][64 * 64];      // 16KB
  __shared__ u16 Vs[2][64 * 64];      // 16KB
  __shared__ u16 Pl[4][16 * 64];      // 8KB

  short8 qf[2];
  {
    const u16* qp = q + (size_t)(b * SS + row0 + lr) * DD + h * HD + g * 8;
    qf[0] = *(const short8*)qp;
    qf[1] = *(const short8*)(qp + 32);
  }
  floatx4 acc[4];
#pragma unroll
  for (int dt = 0; dt < 4; ++dt) acc[dt] = (floatx4){0.f, 0.f, 0.f, 0.f};
  float m = -1e30f, l = 0.f;

  const char* kbase = (const char*)(k + (size_t)(b * SS) * DD + h * HD);
  const char* vbase = (const char*)(vt + (size_t)((b * HH + h) * HD) * SS);
  const int nt = qt + 1;

  auto stage = [&](int t, int buf) {
    const int kvb = t * 64;
#pragma unroll
    for (int p = 0; p < 2; ++p) {
      int L = tid * 16 + p * 4096;
      int row = L >> 7;
      int cb = (L ^ ((row & 7) << 4)) & 127;
      gload_lds16(kbase + (size_t)(kvb + row) * (DD * 2) + cb,
                  (char*)Ks + buf * 8192 + p * 4096 + w * 1024);
      gload_lds16(vbase + (size_t)row * (SS * 2) + kvb * 2 + cb,
                  (char*)Vs + buf * 8192 + p * 4096 + w * 1024);
    }
  };

  stage(0, 0);
  int cur = 0;
  for (int t = 0; t < nt; ++t) {
    __syncthreads();
    if (t + 1 < nt) stage(t + 1, cur ^ 1);
    const u16* kc = Ks[cur];
    const u16* vc = Vs[cur];

    floatx4 sa[4];
#pragma unroll
    for (int ct = 0; ct < 4; ++ct) sa[ct] = (floatx4){0.f, 0.f, 0.f, 0.f};
    __builtin_amdgcn_s_setprio(1);
#pragma unroll
    for (int ks = 0; ks < 2; ++ks) {
      const int c0 = ks * 32 + g * 8;
#pragma unroll
      for (int ct = 0; ct < 4; ++ct) {
        int row = ct * 16 + lr;
        short8 kf = *(const short8*)(kc + row * 64 + (c0 ^ ((row & 7) << 3)));
        sa[ct] = __builtin_amdgcn_mfma_f32_16x16x32_bf16(kf, qf[ks], sa[ct], 0, 0, 0);
      }
    }
    __builtin_amdgcn_s_setprio(0);

    stream_softmax(sa, m, l, acc, Pl[w], t == qt, wlr, g, lr);

    __builtin_amdgcn_s_setprio(1);
#pragma unroll
    for (int ks = 0; ks < 2; ++ks) {
      const int c0 = ks * 32 + g * 8;
      int pby = (lr * 128 + ks * 64 + g * 16) ^ ((lr & 7) << 4);
      short8 pf = *(const short8*)((const char*)Pl[w] + pby);
#pragma unroll
      for (int dt = 0; dt < 4; ++dt) {
        int row = dt * 16 + lr;
        short8 vf = *(const short8*)(vc + row * 64 + (c0 ^ ((row & 7) << 3)));
        acc[dt] = __builtin_amdgcn_mfma_f32_16x16x32_bf16(vf, pf, acc[dt], 0, 0, 0);
      }
    }
    __builtin_amdgcn_s_setprio(0);
    cur ^= 1;
  }

  float inv = 1.0f / l;
#pragma unroll
  for (int dt = 0; dt < 4; ++dt) {
    ushort4v pa = { bconv(acc[dt][0] * inv), bconv(acc[dt][1] * inv),
                    bconv(acc[dt][2] * inv), bconv(acc[dt][3] * inv) };
    *(ushort4v*)(o + (size_t)(b * SS + row0 + lr) * DD + h * HD + dt * 16 + g * 4) = pa;
  }
}

extern "C" void kernel_launch(void* const* d_in, const int* in_sizes, int n_in,
                              void* d_out, int out_size, void* d_ws, size_t ws_size,
                              hipStream_t stream) {
  const float* x  = (const float*)d_in[0];
  // d_in[1] = mask: causal additive -1e9, replicated analytically in-kernel
  const float* Wq = (const float*)d_in[2];
  const float* bq = (const float*)d_in[3];
  const float* Wk = (const float*)d_in[4];
  const float* Wv = (const float*)d_in[5];
  const float* bv = (const float*)d_in[6];
  const float* Wo = (const float*)d_in[7];
  const float* bo = (const float*)d_in[8];
  float* out = (float*)d_out;

  char* ws = (char*)d_ws;
  u16* xb  = (u16*)(ws);                    // 8MB  x bf16 [4096][1024]
  u16* wt  = (u16*)(ws + (8u << 20));       // 8MB  Wq^T,Wk^T,Wv^T,Wo^T bf16
  u16* qkv = (u16*)(ws + (16u << 20));      // 24MB q,k bf16 [4096][1024] (v slab unused)
  u16* vtb = (u16*)(ws + (40u << 20));      // 8MB  v^T per batch [B*D][S] (written by qkv)
  u16* ob  = (u16*)(ws + (48u << 20));      // 8MB  attn out bf16
  u16* wot = wt + 3u * 1024 * 1024;

  dim3 tb(32, 8);
  cvt_bf16x4<<<4096, 256, 0, stream>>>((const float4*)x, (ushort4v*)xb,
                                       (BB * SS * DD) / 4);
  transpose_w<<<dim3(32, 32, 4), tb, 0, stream>>>(Wq, Wk, Wv, Wo, wt);
  gemm_qkv<<<768, 256, 0, stream>>>(xb, wt, qkv, vtb, bq, bv);
  flash_attn<<<1024, 256, 0, stream>>>(qkv, qkv + (size_t)4096 * 1024, vtb, ob);
  gemm_bt<float><<<512, 256, 0, stream>>>(ob, wot, out, bo, 1.0f,
                                          4096, 1024, 1024);
}